// Round 18
// baseline (1722.731 us; speedup 1.0000x reference)
//
#include <hip/hip_runtime.h>
#include <cmath>

#define BB 64
#define TT 250
#define CC 1024
#define GG 1536   // 3U

typedef unsigned long long u64t;
typedef unsigned int uint32;
typedef unsigned short ushort16;
typedef __attribute__((ext_vector_type(8))) short short8v;
typedef __attribute__((ext_vector_type(4))) float f32x4;

// workspace layout (float offsets)
#define O_XGF 0             // [t][g][u][b]; g=0 element (u,b) overwritten by y (same owner thread)
#define O_XGB 24576000      // T*B*G
#define O_UT  49152000      // 2*512*3*512
#define O_MF  50724864      // T*B
#define O_VH  50740864      // u32 {hi16,lo14,tag2} [2 buf][8 grp][16 bhat][512 u] = 131,072 u32
#define O_WT  51003008      // bf16 Wt: hi[2][1536][1024] + lo[2][1536][1024]
#define O_HINT 54148736     // u32 hints[2 dir][4 btile][16 mb][8 wv] = 1024

__device__ __forceinline__ unsigned short f2bf(float f) {
  unsigned u = __float_as_uint(f);
  return (unsigned short)((u + 0x7fffu + ((u >> 16) & 1u)) >> 16);   // RNE
}
__device__ __forceinline__ float bf2f(unsigned short h) {
  return __uint_as_float((unsigned)h << 16);
}
__device__ __forceinline__ void cvt2(float a, float b, uint32& hi, uint32& lo) {
  unsigned short ha = f2bf(a), hb = f2bf(b);
  hi = (uint32)ha | ((uint32)hb << 16);
  lo = (uint32)f2bf(a - bf2f(ha)) | ((uint32)f2bf(b - bf2f(hb)) << 16);
}

// Wt bf16 hi/lo build (must precede the fused gemm dispatch)
__global__ __launch_bounds__(256) void wt_build(
    const float* __restrict__ Wf, const float* __restrict__ Wb,
    ushort16* __restrict__ wt_hi, ushort16* __restrict__ wt_lo)
{
  __shared__ float tile[64][65];
  const int k0 = blockIdx.x * 64;
  const int n0 = blockIdx.y * 64;
  const int d  = blockIdx.z;
  const float* W = d ? Wb : Wf;
  const int l = threadIdx.x & 63, w = threadIdx.x >> 6;
  #pragma unroll
  for (int j = 0; j < 16; j++) {
    int r = j*4 + w;
    tile[r][l] = W[(size_t)(k0+r)*GG + n0 + l];
  }
  __syncthreads();
  #pragma unroll
  for (int j = 0; j < 16; j++) {
    int r = j*4 + w;
    float f = tile[l][r];
    unsigned short h = f2bf(f);
    size_t o = (size_t)(d*GG + n0 + r)*1024 + k0 + l;
    wt_hi[o] = h;
    wt_lo[o] = f2bf(f - bf2f(h));
  }
}

#define LDFRAG(dst, arr, row, kg) do { \
    union { uint4 u; short8v s; } r_; \
    r_.u = *(const uint4*)&arr[(row)*40 + ((kg) << 3)]; \
    dst = r_.s; } while (0)

// Fused prologue: three INDEPENDENT roles, no role waits on another.
//   blocks [0, 3000)      : gemm_xg tile
//   blocks [3000, 3512)   : prep role (vh + hint init, mask decode)
//   blocks [3512, 3896)   : ut transpose role
__global__ __launch_bounds__(256) void fused_prologue(
    const float* __restrict__ X,
    const ushort16* __restrict__ wt_hi, const ushort16* __restrict__ wt_lo,
    const float* __restrict__ bf, const float* __restrict__ bb,
    float* __restrict__ xgf, float* __restrict__ xgb,
    const unsigned char* __restrict__ mraw,
    float* __restrict__ mf, uint32* __restrict__ vh2, uint32* __restrict__ hints,
    const float* __restrict__ Uf, const float* __restrict__ Ub,
    float* __restrict__ ut)
{
  __shared__ __align__(16) char sm[40960];
  const int tid = threadIdx.x;
  const int bidx = blockIdx.x;

  if (bidx >= 3512) {
    // ---------- ut role ----------
    float (*tile)[65] = (float(*)[65])sm;
    const int q  = bidx - 3512;
    const int k0 = (q & 7) * 64;
    const int n0 = ((q >> 3) % 24) * 64;
    const int d  = q / 192;
    const float* Um = d ? Ub : Uf;
    const int l = tid & 63, w = tid >> 6;
    #pragma unroll
    for (int j = 0; j < 16; j++) {
      int r = j*4 + w;
      tile[r][l] = Um[(size_t)(k0+r)*GG + n0 + l];
    }
    __syncthreads();
    #pragma unroll
    for (int j = 0; j < 16; j++) {
      int r = j*4 + w;
      int n = n0 + r, u = n & 511, g = n >> 9;
      ut[(size_t)(((d << 9) | u)*3 + g)*512 + k0 + l] = tile[l][r];
    }
    return;
  }
  if (bidx >= 3000) {
    // ---------- prep role: vh + hint init (graph replays!) + mask decode ----------
    int idx = (bidx - 3000) * 256 + tid;
    if (idx < 131072)                     // tag 0 == step-0 tag; h = 0
      __hip_atomic_store(&vh2[idx], 0u, __ATOMIC_RELAXED, __HIP_MEMORY_SCOPE_AGENT);
    if (idx < 1024)
      __hip_atomic_store(&hints[idx], 0u, __ATOMIC_RELAXED, __HIP_MEMORY_SCOPE_AGENT);
    if (idx < BB*TT) {
      int b = idx / TT, t = idx - b*TT;
      bool bytefmt = (mraw[1] == 1);
      bool mv = bytefmt ? (mraw[idx] != 0) : (((const int*)mraw)[idx] != 0);
      mf[t*BB + b] = mv ? 1.0f : 0.0f;
    }
    return;
  }

  // ---------- gemm role ----------
  ushort16* Ah = (ushort16*)sm;
  ushort16* Al = Ah + 128*40;
  ushort16* Bh = Al + 128*40;
  ushort16* Bl = Bh + 128*40;
  const int l  = tid & 63;
  const int wv = tid >> 6;
  const int wm = wv & 1;
  const int wn = wv >> 1;
  const int t0 = (bidx / 24) * 2;
  const int n0 = (bidx % 24) * 128;
  const int d  = (n0 >= GG) ? 1 : 0;
  const int nl0 = n0 - d*GG;
  const float* bias = d ? bb : bf;
  float* xg = d ? xgb : xgf;

  const int sr = tid >> 1;
  const int sk = (tid & 1) << 4;
  const ushort16* whp = wt_hi + (size_t)(d*GG + nl0 + sr)*1024 + sk;
  const ushort16* wlp = wt_lo + (size_t)(d*GG + nl0 + sr)*1024 + sk;
  const int mrow = (sr & 63)*TT + t0 + (sr >> 6);
  const float* xp = X + (size_t)mrow*CC + sk;

  f32x4 acc[4][4];
  #pragma unroll
  for (int i = 0; i < 4; i++)
    #pragma unroll
    for (int j = 0; j < 4; j++) acc[i][j] = (f32x4){0.f,0.f,0.f,0.f};

  const int kg = l >> 4;
  for (int k0 = 0; k0 < CC; k0 += 32) {
    uint4 ha = *(const uint4*)(whp + k0);
    uint4 hb = *(const uint4*)(whp + k0 + 8);
    uint4 la = *(const uint4*)(wlp + k0);
    uint4 lb = *(const uint4*)(wlp + k0 + 8);
    float4 x0 = *(const float4*)(xp + k0);
    float4 x1 = *(const float4*)(xp + k0 + 4);
    float4 x2 = *(const float4*)(xp + k0 + 8);
    float4 x3 = *(const float4*)(xp + k0 + 12);
    __syncthreads();
    {
      *(uint4*)&Ah[sr*40 + sk]     = ha;
      *(uint4*)&Ah[sr*40 + sk + 8] = hb;
      *(uint4*)&Al[sr*40 + sk]     = la;
      *(uint4*)&Al[sr*40 + sk + 8] = lb;
      uint32 bhv[8], blv[8];
      cvt2(x0.x, x0.y, bhv[0], blv[0]); cvt2(x0.z, x0.w, bhv[1], blv[1]);
      cvt2(x1.x, x1.y, bhv[2], blv[2]); cvt2(x1.z, x1.w, bhv[3], blv[3]);
      cvt2(x2.x, x2.y, bhv[4], blv[4]); cvt2(x2.z, x2.w, bhv[5], blv[5]);
      cvt2(x3.x, x3.y, bhv[6], blv[6]); cvt2(x3.z, x3.w, bhv[7], blv[7]);
      *(uint4*)&Bh[sr*40 + sk]     = make_uint4(bhv[0], bhv[1], bhv[2], bhv[3]);
      *(uint4*)&Bh[sr*40 + sk + 8] = make_uint4(bhv[4], bhv[5], bhv[6], bhv[7]);
      *(uint4*)&Bl[sr*40 + sk]     = make_uint4(blv[0], blv[1], blv[2], blv[3]);
      *(uint4*)&Bl[sr*40 + sk + 8] = make_uint4(blv[4], blv[5], blv[6], blv[7]);
    }
    __syncthreads();
    short8v afh[4], afl[4], bfh[4], bfl[4];
    #pragma unroll
    for (int i = 0; i < 4; i++) {
      const int rA = wn*64 + i*16 + (l & 15);
      LDFRAG(afh[i], Ah, rA, kg);
      LDFRAG(afl[i], Al, rA, kg);
      const int rB = wm*64 + i*16 + (l & 15);
      LDFRAG(bfh[i], Bh, rB, kg);
      LDFRAG(bfl[i], Bl, rB, kg);
    }
    #pragma unroll
    for (int i = 0; i < 4; i++)
      #pragma unroll
      for (int j = 0; j < 4; j++) {
        acc[i][j] = __builtin_amdgcn_mfma_f32_16x16x32_bf16(afh[i], bfh[j], acc[i][j], 0, 0, 0);
        acc[i][j] = __builtin_amdgcn_mfma_f32_16x16x32_bf16(afh[i], bfl[j], acc[i][j], 0, 0, 0);
        acc[i][j] = __builtin_amdgcn_mfma_f32_16x16x32_bf16(afl[i], bfh[j], acc[i][j], 0, 0, 0);
      }
  }
  const int t = t0 + wm;
  #pragma unroll
  for (int i = 0; i < 4; i++) {
    const int ugl = wn*64 + i*16 + ((l >> 4) << 2);
    #pragma unroll
    for (int r = 0; r < 4; r++) {
      const int n = nl0 + ugl + r;
      const float bv = bias[n];
      float* orow = xg + (size_t)t*98304 + ((size_t)(n >> 9) << 15) + ((n & 511) << 6);
      #pragma unroll
      for (int j = 0; j < 4; j++)
        orow[j*16 + (l & 15)] = acc[i][j][r] + bv;
    }
  }
}

// Persistent scan, bf16x3 MFMA. Protocol: speculative payload-first with
// hint-poll fallback; payload element = u32 {hi16, lo14, tag2} (2-bit tag
// mod 4 suffices: ping-pong bounds staleness to 2 generations). Layout
// [buf][grp][bhat16][u512] -> thread's 16 k-values contiguous (8 u64 loads).
__global__ __launch_bounds__(512, 2) void gru_scan(
    float* xgf, float* xgb,
    const float* __restrict__ ut, const float* __restrict__ bf,
    const float* __restrict__ bb, const float* __restrict__ mf,
    uint32* vh2, uint32* hints, float* __restrict__ out)
{
  __shared__ __align__(16) unsigned short Bhi[2][8192];
  __shared__ __align__(16) unsigned short Blo[2][8192];
  const int tid = threadIdx.x;
  const int l   = tid & 63;
  const int wv  = tid >> 6;
  const int bid = blockIdx.x;
  const int d     = bid >> 6;
  const int mb    = (bid >> 2) & 15;
  const int btile = bid & 3;
  const int grp   = (d << 2) | btile;

  short8v af_hi[16], af_lo[16];
  {
    const int row = (wv << 4) | (l & 15);
    const int g   = row & 3;
    const int ua  = (mb << 5) | (row >> 2);
    const int kg_ = (l >> 4) << 3;
    if (g < 3) {
      const float* ap = ut + (((size_t)(((d << 9) | ua) * 3 + g)) << 9);
      #pragma unroll
      for (int ks = 0; ks < 16; ks++)
        #pragma unroll
        for (int j = 0; j < 8; j++) {
          float f = ap[(ks << 5) + kg_ + j];
          unsigned short h = f2bf(f);
          af_hi[ks][j] = (short)h;
          af_lo[ks][j] = (short)f2bf(f - bf2f(h));
        }
    } else {
      #pragma unroll
      for (int ks = 0; ks < 16; ks++)
        #pragma unroll
        for (int j = 0; j < 8; j++) { af_hi[ks][j] = 0; af_lo[ks][j] = 0; }
    }
  }

  const int u  = (mb << 5) | (wv << 2) | (l >> 4);
  const int b  = (btile << 4) | (l & 15);
  const float* bias = (d ? bb : bf) + GG;
  const float b1z = bias[u], b1r = bias[512+u], b1h = bias[1024+u];
  float* xg = d ? xgb : xgf;
  float hprev = 0.0f;

  const int kc  = tid >> 4;              // 0..31: k-range kc*16..+15
  const int blw = tid & 15;              // bhat
  const int ksub_w = kc >> 1;
  const int qbase  = (kc & 1) << 1;
  const int boff = ((l & 15) << 6) + (((l >> 4) ^ ((l >> 1) & 3)) << 4);
  const int ldbase = blw*256 + kc*8;     // u64 index into group slab

  const u64t* hg = (const u64t*)(hints + (grp << 7));
  uint32* myhint = hints + ((grp << 7) | (mb << 3) | wv);

  float xzA, xrA, xhA, mA, xzB, xrB, xhB, mB;
  {
    const int tA = d ? (TT-1) : 0;
    const float* p = xg + (size_t)tA*98304 + (u << 6) + b;
    xzA = p[0]; xrA = p[32768]; xhA = p[65536]; mA = mf[tA*BB + b];
    const int tB = d ? (TT-2) : 1;
    const float* q = xg + (size_t)tB*98304 + (u << 6) + b;
    xzB = q[0]; xrB = q[32768]; xhB = q[65536]; mB = mf[tB*BB + b];
  }

  for (int s = 0; s < TT; s++) {
    const unsigned tg = (unsigned)s & 3u;
    const int t = d ? (TT-1-s) : s;
    u64t* vin = (u64t*)(vh2 + ((size_t)((((unsigned)s & 1u) << 3) | (unsigned)grp) << 13));

    // ---- speculative payload load: 8 u64 (16 elements), tags verified ----
    u64t v[8];
    #pragma unroll
    for (int i = 0; i < 8; i++)
      v[i] = __hip_atomic_load(vin + ldbase + i, __ATOMIC_RELAXED, __HIP_MEMORY_SCOPE_AGENT);
    int bad = 0;
    #pragma unroll
    for (int i = 0; i < 8; i++)
      bad |= (((unsigned)v[i] & 3u) != tg) | (((unsigned)(v[i] >> 32) & 3u) != tg);
    if (__any(bad)) {
      // fallback: cheap hint-poll wait, then reload stale words
      const unsigned us_ = (unsigned)s;
      while (true) {
        u64t hv = __hip_atomic_load(&hg[l], __ATOMIC_RELAXED, __HIP_MEMORY_SCOPE_AGENT);
        if (__all(((unsigned)hv >= us_) && ((unsigned)(hv >> 32) >= us_))) break;
        __builtin_amdgcn_s_sleep(1);
      }
      asm volatile("" ::: "memory");
      while (true) {
        #pragma unroll
        for (int i = 0; i < 8; i++)
          if ((((unsigned)v[i] & 3u) != tg) | (((unsigned)(v[i] >> 32) & 3u) != tg))
            v[i] = __hip_atomic_load(vin + ldbase + i, __ATOMIC_RELAXED, __HIP_MEMORY_SCOPE_AGENT);
        int bad2 = 0;
        #pragma unroll
        for (int i = 0; i < 8; i++)
          bad2 |= (((unsigned)v[i] & 3u) != tg) | (((unsigned)(v[i] >> 32) & 3u) != tg);
        if (!__any(bad2)) break;
        __builtin_amdgcn_s_sleep(1);
      }
    }

    unsigned short* BhiS = Bhi[s & 1];
    unsigned short* BloS = Blo[s & 1];
    #pragma unroll
    for (int half = 0; half < 2; half++) {
      uint32 hw[4], lw[4];
      #pragma unroll
      for (int p = 0; p < 4; p++) {
        u64t vv = v[(half << 2) + p];
        uint32 w0 = (uint32)vv;
        uint32 w1 = (uint32)(vv >> 32);
        hw[p] = (w0 >> 16) | (w1 & 0xffff0000u);
        lw[p] = (w0 & 0xfffcu) | ((w1 & 0xfffcu) << 16);
      }
      const int phys = (qbase + half) ^ ((blw >> 1) & 3);
      const int off = (ksub_w << 10) + (blw << 6) + (phys << 4);
      *(uint4*)((char*)BhiS + off) = make_uint4(hw[0], hw[1], hw[2], hw[3]);
      *(uint4*)((char*)BloS + off) = make_uint4(lw[0], lw[1], lw[2], lw[3]);
    }
    __syncthreads();

    float xzC = 0.f, xrC = 0.f, xhC = 0.f, mC = 0.f;
    if (s+2 < TT) {
      const int t2 = d ? (TT-3-s) : (s+2);
      const float* xp = xg + (size_t)t2*98304 + (u << 6) + b;
      xzC = xp[0]; xrC = xp[32768]; xhC = xp[65536];
      mC  = mf[t2*BB + b];
    }

    f32x4 acc0 = {0.f,0.f,0.f,0.f};
    f32x4 acc1 = {0.f,0.f,0.f,0.f};
    f32x4 acc2 = {0.f,0.f,0.f,0.f};
    #pragma unroll
    for (int ks = 0; ks < 16; ks++) {
      short8v bh  = *(const short8v*)((const char*)BhiS + (ks << 10) + boff);
      short8v bl8 = *(const short8v*)((const char*)BloS + (ks << 10) + boff);
      acc0 = __builtin_amdgcn_mfma_f32_16x16x32_bf16(af_hi[ks], bh,  acc0, 0, 0, 0);
      acc1 = __builtin_amdgcn_mfma_f32_16x16x32_bf16(af_hi[ks], bl8, acc1, 0, 0, 0);
      acc2 = __builtin_amdgcn_mfma_f32_16x16x32_bf16(af_lo[ks], bh,  acc2, 0, 0, 0);
    }
    float az = acc0[0] + acc1[0] + acc2[0];
    float ar = acc0[1] + acc1[1] + acc2[1];
    float ah = acc0[2] + acc1[2] + acc2[2];

    float z  = 1.0f / (1.0f + expf(-(xzA + az + b1z)));
    float r  = 1.0f / (1.0f + expf(-(xrA + ar + b1r)));
    float cc = tanhf(xhA + r * (ah + b1h));
    float hn = z*hprev + (1.0f - z)*cc;
    hn = (mA != 0.0f) ? hn : hprev;
    hprev = hn;

    // publish u32 {hi16, lo14, tag2}, then fire-and-forget hint, then y
    uint32* vout = vh2 + ((size_t)(((((unsigned)s + 1u) & 1u) << 3) | (unsigned)grp) << 13);
    unsigned short hh = f2bf(hn);
    unsigned short hl = f2bf(hn - bf2f(hh));
    uint32 pk = ((uint32)hh << 16) | ((uint32)hl & 0xfffcu) | (((uint32)(s+1)) & 3u);
    __hip_atomic_store(&vout[((l & 15) << 9) | u], pk, __ATOMIC_RELAXED, __HIP_MEMORY_SCOPE_AGENT);
    asm volatile("" ::: "memory");
    if (l == 0)
      __hip_atomic_store(myhint, (uint32)(s + 1), __ATOMIC_RELAXED, __HIP_MEMORY_SCOPE_AGENT);
    xg[(size_t)t*98304 + ((size_t)u << 6) + b] = hn;
    xzA = xzB; xrA = xrB; xhA = xhB; mA = mB;
    xzB = xzC; xrB = xrC; xhB = xhC; mB = mC;
  }
  out[16384000ull + ((size_t)b << 10) + (d << 9) + u] = hprev;
}

// out[b][t][d*512+u] <- y stored as [t][u][b] inside xg g=0 regions
__global__ __launch_bounds__(256) void y_transpose(
    const float* __restrict__ xgf, const float* __restrict__ xgb,
    float* __restrict__ out)
{
  __shared__ float tile[64][65];
  const int t  = blockIdx.x;
  const int ch = blockIdx.y;
  const int d  = ch >> 3, uc = ch & 7;
  const float* src = (d ? xgb : xgf) + (size_t)t*98304 + (size_t)uc*4096;
  const int lane = threadIdx.x & 63, w = threadIdx.x >> 6;
  #pragma unroll
  for (int j = 0; j < 16; j++) {
    int r = j*4 + w;
    tile[r][lane] = src[r*64 + lane];
  }
  __syncthreads();
  #pragma unroll
  for (int j = 0; j < 16; j++) {
    int b = j*4 + w;
    out[((size_t)b*TT + t)*1024 + (d << 9) + (uc << 6) + lane] = tile[lane][b];
  }
}

extern "C" void kernel_launch(void* const* d_in, const int* in_sizes, int n_in,
                              void* d_out, int out_size, void* d_ws, size_t ws_size,
                              hipStream_t stream) {
  const float* X  = (const float*)d_in[0];
  const unsigned char* Mk = (const unsigned char*)d_in[1];
  const float* Wf = (const float*)d_in[2];
  const float* Uf = (const float*)d_in[3];
  const float* bf = (const float*)d_in[4];
  const float* Wb = (const float*)d_in[5];
  const float* Ub = (const float*)d_in[6];
  const float* bb = (const float*)d_in[7];
  float* out = (float*)d_out;
  float* ws  = (float*)d_ws;
  float* xgf = ws + O_XGF;
  float* xgb = ws + O_XGB;
  float* ut  = ws + O_UT;
  float* mf  = ws + O_MF;
  uint32* vh2 = (uint32*)(ws + O_VH);
  uint32* hints = (uint32*)(ws + O_HINT);
  ushort16* wt_hi = (ushort16*)(ws + O_WT);
  ushort16* wt_lo = wt_hi + (size_t)2*GG*1024;

  wt_build<<<dim3(16, 24, 2), dim3(256), 0, stream>>>(Wf, Wb, wt_hi, wt_lo);
  fused_prologue<<<dim3(3896), dim3(256), 0, stream>>>(
      X, wt_hi, wt_lo, bf, bb, xgf, xgb, Mk, mf, vh2, hints, Uf, Ub, ut);
  gru_scan<<<dim3(128), dim3(512), 0, stream>>>(xgf, xgb, ut, bf, bb, mf, vh2, hints, out);
  y_transpose<<<dim3(TT, 16), dim3(256), 0, stream>>>(xgf, xgb, out);
}

// Round 19
// 1276.905 us; speedup vs baseline: 1.3491x; 1.3491x over previous
//
#include <hip/hip_runtime.h>
#include <cmath>

#define BB 64
#define TT 250
#define CC 1024
#define GG 1536   // 3U

typedef unsigned long long u64t;
typedef unsigned int uint32;
typedef unsigned short ushort16;
typedef __attribute__((ext_vector_type(8))) short short8v;
typedef __attribute__((ext_vector_type(4))) float f32x4;

// workspace layout (float offsets)
#define O_XGF 0             // [t][g][u][b]; g=0 element (u,b) overwritten by y (same owner thread)
#define O_XGB 24576000      // T*B*G
#define O_UT  49152000      // 2*512*3*512
#define O_MF  50724864      // T*B
#define O_VH  50740864      // u64 {tag32,hi16,lo16} [2 buf][2 dir][512 u][64 b] = 131,072 u64
#define O_WT  51003008      // bf16 Wt: hi[2][1536][1024] + lo[2][1536][1024]
#define O_HINT 54148736     // u32 hints[2 dir][4 btile][16 mb][8 wv] = 1024

__device__ __forceinline__ unsigned short f2bf(float f) {
  unsigned u = __float_as_uint(f);
  return (unsigned short)((u + 0x7fffu + ((u >> 16) & 1u)) >> 16);   // RNE
}
__device__ __forceinline__ float bf2f(unsigned short h) {
  return __uint_as_float((unsigned)h << 16);
}
__device__ __forceinline__ void cvt2(float a, float b, uint32& hi, uint32& lo) {
  unsigned short ha = f2bf(a), hb = f2bf(b);
  hi = (uint32)ha | ((uint32)hb << 16);
  lo = (uint32)f2bf(a - bf2f(ha)) | ((uint32)f2bf(b - bf2f(hb)) << 16);
}

// Wt bf16 hi/lo build (must precede the fused gemm dispatch)
__global__ __launch_bounds__(256) void wt_build(
    const float* __restrict__ Wf, const float* __restrict__ Wb,
    ushort16* __restrict__ wt_hi, ushort16* __restrict__ wt_lo)
{
  __shared__ float tile[64][65];
  const int k0 = blockIdx.x * 64;
  const int n0 = blockIdx.y * 64;
  const int d  = blockIdx.z;
  const float* W = d ? Wb : Wf;
  const int l = threadIdx.x & 63, w = threadIdx.x >> 6;
  #pragma unroll
  for (int j = 0; j < 16; j++) {
    int r = j*4 + w;
    tile[r][l] = W[(size_t)(k0+r)*GG + n0 + l];
  }
  __syncthreads();
  #pragma unroll
  for (int j = 0; j < 16; j++) {
    int r = j*4 + w;
    float f = tile[l][r];
    unsigned short h = f2bf(f);
    size_t o = (size_t)(d*GG + n0 + r)*1024 + k0 + l;
    wt_hi[o] = h;
    wt_lo[o] = f2bf(f - bf2f(h));
  }
}

#define LDFRAG(dst, arr, row, kg) do { \
    union { uint4 u; short8v s; } r_; \
    r_.u = *(const uint4*)&arr[(row)*40 + ((kg) << 3)]; \
    dst = r_.s; } while (0)

// Fused prologue: three INDEPENDENT roles, no role waits on another.
//   blocks [0, 3000)      : gemm_xg tile
//   blocks [3000, 3512)   : prep role (vh + hint init, mask decode)
//   blocks [3512, 3896)   : ut transpose role
__global__ __launch_bounds__(256) void fused_prologue(
    const float* __restrict__ X,
    const ushort16* __restrict__ wt_hi, const ushort16* __restrict__ wt_lo,
    const float* __restrict__ bf, const float* __restrict__ bb,
    float* __restrict__ xgf, float* __restrict__ xgb,
    const unsigned char* __restrict__ mraw,
    float* __restrict__ mf, u64t* __restrict__ vh, uint32* __restrict__ hints,
    const float* __restrict__ Uf, const float* __restrict__ Ub,
    float* __restrict__ ut)
{
  __shared__ __align__(16) char sm[40960];
  const int tid = threadIdx.x;
  const int bidx = blockIdx.x;

  if (bidx >= 3512) {
    // ---------- ut role ----------
    float (*tile)[65] = (float(*)[65])sm;
    const int q  = bidx - 3512;
    const int k0 = (q & 7) * 64;
    const int n0 = ((q >> 3) % 24) * 64;
    const int d  = q / 192;
    const float* Um = d ? Ub : Uf;
    const int l = tid & 63, w = tid >> 6;
    #pragma unroll
    for (int j = 0; j < 16; j++) {
      int r = j*4 + w;
      tile[r][l] = Um[(size_t)(k0+r)*GG + n0 + l];
    }
    __syncthreads();
    #pragma unroll
    for (int j = 0; j < 16; j++) {
      int r = j*4 + w;
      int n = n0 + r, u = n & 511, g = n >> 9;
      ut[(size_t)(((d << 9) | u)*3 + g)*512 + k0 + l] = tile[l][r];
    }
    return;
  }
  if (bidx >= 3000) {
    // ---------- prep role: vh + hint init (graph replays!) + mask decode ----------
    int idx = (bidx - 3000) * 256 + tid;
    if (idx < 131072)
      __hip_atomic_store(&vh[idx], 0ULL, __ATOMIC_RELAXED, __HIP_MEMORY_SCOPE_AGENT);
    if (idx < 1024)
      __hip_atomic_store(&hints[idx], 0u, __ATOMIC_RELAXED, __HIP_MEMORY_SCOPE_AGENT);
    if (idx < BB*TT) {
      int b = idx / TT, t = idx - b*TT;
      bool bytefmt = (mraw[1] == 1);
      bool mv = bytefmt ? (mraw[idx] != 0) : (((const int*)mraw)[idx] != 0);
      mf[t*BB + b] = mv ? 1.0f : 0.0f;
    }
    return;
  }

  // ---------- gemm role ----------
  ushort16* Ah = (ushort16*)sm;
  ushort16* Al = Ah + 128*40;
  ushort16* Bh = Al + 128*40;
  ushort16* Bl = Bh + 128*40;
  const int l  = tid & 63;
  const int wv = tid >> 6;
  const int wm = wv & 1;
  const int wn = wv >> 1;
  const int t0 = (bidx / 24) * 2;
  const int n0 = (bidx % 24) * 128;
  const int d  = (n0 >= GG) ? 1 : 0;
  const int nl0 = n0 - d*GG;
  const float* bias = d ? bb : bf;
  float* xg = d ? xgb : xgf;

  const int sr = tid >> 1;
  const int sk = (tid & 1) << 4;
  const ushort16* whp = wt_hi + (size_t)(d*GG + nl0 + sr)*1024 + sk;
  const ushort16* wlp = wt_lo + (size_t)(d*GG + nl0 + sr)*1024 + sk;
  const int mrow = (sr & 63)*TT + t0 + (sr >> 6);
  const float* xp = X + (size_t)mrow*CC + sk;

  f32x4 acc[4][4];
  #pragma unroll
  for (int i = 0; i < 4; i++)
    #pragma unroll
    for (int j = 0; j < 4; j++) acc[i][j] = (f32x4){0.f,0.f,0.f,0.f};

  const int kg = l >> 4;
  for (int k0 = 0; k0 < CC; k0 += 32) {
    uint4 ha = *(const uint4*)(whp + k0);
    uint4 hb = *(const uint4*)(whp + k0 + 8);
    uint4 la = *(const uint4*)(wlp + k0);
    uint4 lb = *(const uint4*)(wlp + k0 + 8);
    float4 x0 = *(const float4*)(xp + k0);
    float4 x1 = *(const float4*)(xp + k0 + 4);
    float4 x2 = *(const float4*)(xp + k0 + 8);
    float4 x3 = *(const float4*)(xp + k0 + 12);
    __syncthreads();
    {
      *(uint4*)&Ah[sr*40 + sk]     = ha;
      *(uint4*)&Ah[sr*40 + sk + 8] = hb;
      *(uint4*)&Al[sr*40 + sk]     = la;
      *(uint4*)&Al[sr*40 + sk + 8] = lb;
      uint32 bhv[8], blv[8];
      cvt2(x0.x, x0.y, bhv[0], blv[0]); cvt2(x0.z, x0.w, bhv[1], blv[1]);
      cvt2(x1.x, x1.y, bhv[2], blv[2]); cvt2(x1.z, x1.w, bhv[3], blv[3]);
      cvt2(x2.x, x2.y, bhv[4], blv[4]); cvt2(x2.z, x2.w, bhv[5], blv[5]);
      cvt2(x3.x, x3.y, bhv[6], blv[6]); cvt2(x3.z, x3.w, bhv[7], blv[7]);
      *(uint4*)&Bh[sr*40 + sk]     = make_uint4(bhv[0], bhv[1], bhv[2], bhv[3]);
      *(uint4*)&Bh[sr*40 + sk + 8] = make_uint4(bhv[4], bhv[5], bhv[6], bhv[7]);
      *(uint4*)&Bl[sr*40 + sk]     = make_uint4(blv[0], blv[1], blv[2], blv[3]);
      *(uint4*)&Bl[sr*40 + sk + 8] = make_uint4(blv[4], blv[5], blv[6], blv[7]);
    }
    __syncthreads();
    short8v afh[4], afl[4], bfh[4], bfl[4];
    #pragma unroll
    for (int i = 0; i < 4; i++) {
      const int rA = wn*64 + i*16 + (l & 15);
      LDFRAG(afh[i], Ah, rA, kg);
      LDFRAG(afl[i], Al, rA, kg);
      const int rB = wm*64 + i*16 + (l & 15);
      LDFRAG(bfh[i], Bh, rB, kg);
      LDFRAG(bfl[i], Bl, rB, kg);
    }
    #pragma unroll
    for (int i = 0; i < 4; i++)
      #pragma unroll
      for (int j = 0; j < 4; j++) {
        acc[i][j] = __builtin_amdgcn_mfma_f32_16x16x32_bf16(afh[i], bfh[j], acc[i][j], 0, 0, 0);
        acc[i][j] = __builtin_amdgcn_mfma_f32_16x16x32_bf16(afh[i], bfl[j], acc[i][j], 0, 0, 0);
        acc[i][j] = __builtin_amdgcn_mfma_f32_16x16x32_bf16(afl[i], bfh[j], acc[i][j], 0, 0, 0);
      }
  }
  const int t = t0 + wm;
  #pragma unroll
  for (int i = 0; i < 4; i++) {
    const int ugl = wn*64 + i*16 + ((l >> 4) << 2);
    #pragma unroll
    for (int r = 0; r < 4; r++) {
      const int n = nl0 + ugl + r;
      const float bv = bias[n];
      float* orow = xg + (size_t)t*98304 + ((size_t)(n >> 9) << 15) + ((n & 511) << 6);
      #pragma unroll
      for (int j = 0; j < 4; j++)
        orow[j*16 + (l & 15)] = acc[i][j][r] + bv;
    }
  }
}

// Persistent scan, bf16x3 MFMA. Protocol: SPECULATIVE payload-first (tags
// verified always) with hint-poll fallback as the cheap wait. Common case
// (producers ahead) = single L3 round trip for data, no hint trip.
__global__ __launch_bounds__(512, 2) void gru_scan(
    float* xgf, float* xgb,
    const float* __restrict__ ut, const float* __restrict__ bf,
    const float* __restrict__ bb, const float* __restrict__ mf,
    u64t* vh, uint32* hints, float* __restrict__ out)
{
  __shared__ __align__(16) unsigned short Bhi[2][8192];
  __shared__ __align__(16) unsigned short Blo[2][8192];
  const int tid = threadIdx.x;
  const int l   = tid & 63;
  const int wv  = tid >> 6;
  const int bid = blockIdx.x;
  const int d     = bid >> 6;
  const int mb    = (bid >> 2) & 15;
  const int btile = bid & 3;

  short8v af_hi[16], af_lo[16];
  {
    const int row = (wv << 4) | (l & 15);
    const int g   = row & 3;
    const int ua  = (mb << 5) | (row >> 2);
    const int kg_ = (l >> 4) << 3;
    if (g < 3) {
      const float* ap = ut + (((size_t)(((d << 9) | ua) * 3 + g)) << 9);
      #pragma unroll
      for (int ks = 0; ks < 16; ks++)
        #pragma unroll
        for (int j = 0; j < 8; j++) {
          float f = ap[(ks << 5) + kg_ + j];
          unsigned short h = f2bf(f);
          af_hi[ks][j] = (short)h;
          af_lo[ks][j] = (short)f2bf(f - bf2f(h));
        }
    } else {
      #pragma unroll
      for (int ks = 0; ks < 16; ks++)
        #pragma unroll
        for (int j = 0; j < 8; j++) { af_hi[ks][j] = 0; af_lo[ks][j] = 0; }
    }
  }

  const int u  = (mb << 5) | (wv << 2) | (l >> 4);
  const int b  = (btile << 4) | (l & 15);
  const float* bias = (d ? bb : bf) + GG;
  const float b1z = bias[u], b1r = bias[512+u], b1h = bias[1024+u];
  float* xg = d ? xgb : xgf;
  float hprev = 0.0f;

  const int kc  = tid >> 4;
  const int blw = tid & 15;
  const int cb  = (btile << 4) | blw;
  const int ksub_w = kc >> 1;
  const int qbase  = (kc & 1) << 1;
  const int boff = ((l & 15) << 6) + (((l >> 4) ^ ((l >> 1) & 3)) << 4);

  const u64t* hg = (const u64t*)(hints + (((d << 2) | btile) << 7));
  uint32* myhint = hints + ((((d << 2) | btile) << 7) | (mb << 3) | wv);

  float xzA, xrA, xhA, mA, xzB, xrB, xhB, mB;
  {
    const int tA = d ? (TT-1) : 0;
    const float* p = xg + (size_t)tA*98304 + (u << 6) + b;
    xzA = p[0]; xrA = p[32768]; xhA = p[65536]; mA = mf[tA*BB + b];
    const int tB = d ? (TT-2) : 1;
    const float* q = xg + (size_t)tB*98304 + (u << 6) + b;
    xzB = q[0]; xrB = q[32768]; xhB = q[65536]; mB = mf[tB*BB + b];
  }

  for (int s = 0; s < TT; s++) {
    const unsigned us_ = (unsigned)s;
    const int t = d ? (TT-1-s) : s;
    u64t* vin = vh + (size_t)((((unsigned)s & 1u) << 1) | (unsigned)d) * 32768;

    // ---- speculative payload load (tags always verified) ----
    u64t v[16];
    #pragma unroll
    for (int i = 0; i < 16; i++)
      v[i] = __hip_atomic_load(vin + ((kc << 4) + i)*64 + cb, __ATOMIC_RELAXED, __HIP_MEMORY_SCOPE_AGENT);
    int bad = 0;
    #pragma unroll
    for (int i = 0; i < 16; i++) bad |= ((unsigned)(v[i] >> 32) < us_) ? 1 : 0;
    if (__any(bad)) {
      // fallback: cheap hint-poll wait, then reload stale words
      while (true) {
        u64t hv = __hip_atomic_load(&hg[l], __ATOMIC_RELAXED, __HIP_MEMORY_SCOPE_AGENT);
        if (__all(((unsigned)hv >= us_) && ((unsigned)(hv >> 32) >= us_))) break;
        __builtin_amdgcn_s_sleep(1);
      }
      asm volatile("" ::: "memory");
      while (true) {
        #pragma unroll
        for (int i = 0; i < 16; i++)
          if ((unsigned)(v[i] >> 32) < us_)
            v[i] = __hip_atomic_load(vin + ((kc << 4) + i)*64 + cb, __ATOMIC_RELAXED, __HIP_MEMORY_SCOPE_AGENT);
        int bad2 = 0;
        #pragma unroll
        for (int i = 0; i < 16; i++) bad2 |= ((unsigned)(v[i] >> 32) < us_) ? 1 : 0;
        if (!__any(bad2)) break;
        __builtin_amdgcn_s_sleep(1);
      }
    }

    unsigned short* BhiS = Bhi[s & 1];
    unsigned short* BloS = Blo[s & 1];
    #pragma unroll
    for (int half = 0; half < 2; half++) {
      uint32 hw[4], lw[4];
      #pragma unroll
      for (int p = 0; p < 4; p++) {
        u64t v0 = v[(half << 3) + (p << 1)];
        u64t v1 = v[(half << 3) + (p << 1) + 1];
        hw[p] = (uint32)((v0 >> 16) & 0xffffu) | ((uint32)((v1 >> 16) & 0xffffu) << 16);
        lw[p] = (uint32)(v0 & 0xffffu)         | ((uint32)(v1 & 0xffffu) << 16);
      }
      const int phys = (qbase + half) ^ ((blw >> 1) & 3);
      const int off = (ksub_w << 10) + (blw << 6) + (phys << 4);
      *(uint4*)((char*)BhiS + off) = make_uint4(hw[0], hw[1], hw[2], hw[3]);
      *(uint4*)((char*)BloS + off) = make_uint4(lw[0], lw[1], lw[2], lw[3]);
    }
    __syncthreads();

    float xzC = 0.f, xrC = 0.f, xhC = 0.f, mC = 0.f;
    if (s+2 < TT) {
      const int t2 = d ? (TT-3-s) : (s+2);
      const float* xp = xg + (size_t)t2*98304 + (u << 6) + b;
      xzC = xp[0]; xrC = xp[32768]; xhC = xp[65536];
      mC  = mf[t2*BB + b];
    }

    f32x4 acc0 = {0.f,0.f,0.f,0.f};
    f32x4 acc1 = {0.f,0.f,0.f,0.f};
    f32x4 acc2 = {0.f,0.f,0.f,0.f};
    #pragma unroll
    for (int ks = 0; ks < 16; ks++) {
      short8v bh  = *(const short8v*)((const char*)BhiS + (ks << 10) + boff);
      short8v bl8 = *(const short8v*)((const char*)BloS + (ks << 10) + boff);
      acc0 = __builtin_amdgcn_mfma_f32_16x16x32_bf16(af_hi[ks], bh,  acc0, 0, 0, 0);
      acc1 = __builtin_amdgcn_mfma_f32_16x16x32_bf16(af_hi[ks], bl8, acc1, 0, 0, 0);
      acc2 = __builtin_amdgcn_mfma_f32_16x16x32_bf16(af_lo[ks], bh,  acc2, 0, 0, 0);
    }
    float az = acc0[0] + acc1[0] + acc2[0];
    float ar = acc0[1] + acc1[1] + acc2[1];
    float ah = acc0[2] + acc1[2] + acc2[2];

    float z  = 1.0f / (1.0f + expf(-(xzA + az + b1z)));
    float r  = 1.0f / (1.0f + expf(-(xrA + ar + b1r)));
    float cc = tanhf(xhA + r * (ah + b1h));
    float hn = z*hprev + (1.0f - z)*cc;
    hn = (mA != 0.0f) ? hn : hprev;
    hprev = hn;

    u64t* vout = vh + (size_t)(((((unsigned)s + 1u) & 1u) << 1) | (unsigned)d) * 32768;
    unsigned short hh = f2bf(hn);
    unsigned short hl = f2bf(hn - bf2f(hh));
    u64t pk = ((u64t)(unsigned)(s+1) << 32) | ((u64t)hh << 16) | (u64t)hl;
    __hip_atomic_store(&vout[(u << 6) | b], pk, __ATOMIC_RELAXED, __HIP_MEMORY_SCOPE_AGENT);
    asm volatile("" ::: "memory");
    if (l == 0)
      __hip_atomic_store(myhint, (uint32)(s + 1), __ATOMIC_RELAXED, __HIP_MEMORY_SCOPE_AGENT);
    xg[(size_t)t*98304 + ((size_t)u << 6) + b] = hn;
    xzA = xzB; xrA = xrB; xhA = xhB; mA = mB;
    xzB = xzC; xrB = xrC; xhB = xhC; mB = mC;
  }
  out[16384000ull + ((size_t)b << 10) + (d << 9) + u] = hprev;
}

// out[b][t][d*512+u] <- y stored as [t][u][b] inside xg g=0 regions
__global__ __launch_bounds__(256) void y_transpose(
    const float* __restrict__ xgf, const float* __restrict__ xgb,
    float* __restrict__ out)
{
  __shared__ float tile[64][65];
  const int t  = blockIdx.x;
  const int ch = blockIdx.y;
  const int d  = ch >> 3, uc = ch & 7;
  const float* src = (d ? xgb : xgf) + (size_t)t*98304 + (size_t)uc*4096;
  const int lane = threadIdx.x & 63, w = threadIdx.x >> 6;
  #pragma unroll
  for (int j = 0; j < 16; j++) {
    int r = j*4 + w;
    tile[r][lane] = src[r*64 + lane];
  }
  __syncthreads();
  #pragma unroll
  for (int j = 0; j < 16; j++) {
    int b = j*4 + w;
    out[((size_t)b*TT + t)*1024 + (d << 9) + (uc << 6) + lane] = tile[lane][b];
  }
}

extern "C" void kernel_launch(void* const* d_in, const int* in_sizes, int n_in,
                              void* d_out, int out_size, void* d_ws, size_t ws_size,
                              hipStream_t stream) {
  const float* X  = (const float*)d_in[0];
  const unsigned char* Mk = (const unsigned char*)d_in[1];
  const float* Wf = (const float*)d_in[2];
  const float* Uf = (const float*)d_in[3];
  const float* bf = (const float*)d_in[4];
  const float* Wb = (const float*)d_in[5];
  const float* Ub = (const float*)d_in[6];
  const float* bb = (const float*)d_in[7];
  float* out = (float*)d_out;
  float* ws  = (float*)d_ws;
  float* xgf = ws + O_XGF;
  float* xgb = ws + O_XGB;
  float* ut  = ws + O_UT;
  float* mf  = ws + O_MF;
  u64t*  vh  = (u64t*)(ws + O_VH);
  uint32* hints = (uint32*)(ws + O_HINT);
  ushort16* wt_hi = (ushort16*)(ws + O_WT);
  ushort16* wt_lo = wt_hi + (size_t)2*GG*1024;

  wt_build<<<dim3(16, 24, 2), dim3(256), 0, stream>>>(Wf, Wb, wt_hi, wt_lo);
  fused_prologue<<<dim3(3896), dim3(256), 0, stream>>>(
      X, wt_hi, wt_lo, bf, bb, xgf, xgb, Mk, mf, vh, hints, Uf, Ub, ut);
  gru_scan<<<dim3(128), dim3(512), 0, stream>>>(xgf, xgb, ut, bf, bb, mf, vh, hints, out);
  y_transpose<<<dim3(TT, 16), dim3(256), 0, stream>>>(xgf, xgb, out);
}